// Round 2
// baseline (232.563 us; speedup 1.0000x reference)
//
#include <hip/hip_runtime.h>

// Problem constants
#define H   16
#define E   300
#define D   768
#define HD  48
#define QL  64
#define KL  64
#define NH  64          // n(4) * h(16)
#define ROWS 384        // 256 Q rows + 64 K + 64 V
#define SPLITK 12
#define NCH 16          // e-chunk partial count for main
#define NBLK 256        // grid size (1 block/CU; capacity 2/CU guaranteed)

// Workspace float offsets
#define OFF_PP 0                              // Ppart[12][384][768]
#define OFF_PF (SPLITK*ROWS*D)                // 3,538,944  Pf[384][768]
#define OFF_A  (OFF_PF + ROWS*D)              // 3,833,856  A[nh][e][q]
#define OFF_B  (OFF_A + NH*E*QL)              // 5,062,656  B[nh][k][q]
#define OFF_SP (OFF_B + NH*KL*QL)             // 5,324,800  Sp[16][nh][q][k]
#define OFF_BAR (OFF_SP + NCH*NH*QL*KL)       // 9,519,104  4 uint barrier counters
// end = 9,519,108 floats = 38.1 MB

// Shared-memory union: one allocation reused across phases (max 49.7 KB).
union SharedU {
    struct { float XsT[32][132]; float Ws2[2][32][128]; } p1;   // 49.7 KB
    struct { float RsT[48][132]; float QsT[48][68]; } p3;       // 38.4 KB
    struct { float As[75 * 64]; float Bs[64][68]; } p4;         // 36.6 KB
    struct { float S_l[16][64]; float V_l[64][52]; } p5;        // 17.4 KB
};

// One-shot grid barrier: per-site counter (zeroed by hipMemsetAsync each
// launch).  Release: __threadfence() before the arrive-inc writes back this
// XCD's L2 (covers all blockmates' stores - block lives on one CU/XCD).
// Acquire: __threadfence() after the spin invalidates stale clean L2 lines.
// Safe without cooperative launch because grid(256) <= guaranteed capacity
// (launch_bounds(256,2) -> VGPR<=256 -> 2 blocks/CU; LDS 49.7KB -> 3/CU).
__device__ __forceinline__ void grid_barrier(unsigned* __restrict__ bar, int site)
{
    __syncthreads();
    if (threadIdx.x == 0) {
        __threadfence();
        const unsigned arrived = atomicAdd(&bar[site], 1u) + 1u;
        if (arrived < NBLK) {
            while (atomicAdd(&bar[site], 0u) < NBLK)
                __builtin_amdgcn_s_sleep(8);
        }
        __threadfence();
    }
    __syncthreads();
}

// ---------------------------------------------------------------------------
// Fully fused pipeline: 5 phases separated by software grid barriers instead
// of 5 kernel dispatches.  grid = 256 blocks, 256 threads.  Phase bodies are
// identical to the verified 5-kernel version; only blockIdx->job mapping and
// the barrier plumbing differ.
// ---------------------------------------------------------------------------
__global__ __launch_bounds__(256, 2) void fused_kernel(
    const float* __restrict__ qin, const float* __restrict__ kin, const float* __restrict__ vin,
    const float* __restrict__ Wq, const float* __restrict__ Wk, const float* __restrict__ Wv,
    const float* __restrict__ bq, const float* __restrict__ bk, const float* __restrict__ bv,
    const float* __restrict__ memo, float* __restrict__ ws, float* __restrict__ outp)
{
    __shared__ SharedU sh;
    unsigned* bar = (unsigned*)(ws + OFF_BAR);
    const int bid = blockIdx.x;
    const int tid = threadIdx.x;

    // -----------------------------------------------------------------
    // Phase 1: QKV projection.  216 jobs = (3 rowblk, 6 colblk, 12 ks).
    // BM=128 BN=128, K-chunk 64 per splitK slice, 8x8 microtile.
    // -----------------------------------------------------------------
    if (bid < 216) {
        const int rowblk = bid / 72;              // 0..2
        const int colblk = (bid % 72) / 12;       // 0..5
        const int ks     = bid % 12;              // 0..11
        const int col0   = colblk * 128;
        const int kbase  = ks * 64;

        const int g0 = rowblk * 128;
        const float* Wlo = (g0      < 256) ? Wq : (g0      < 320) ? Wk : Wv;
        const float* Whi = (g0 + 64 < 256) ? Wq : (g0 + 64 < 320) ? Wk : Wv;

        const int r0 = (tid >> 4) * 8;            // 0..120
        const int c0 = (tid & 15) * 8;            // 0..120
        const int hw = r0 >> 6;                   // wave-uniform W-half select

        float acc[8][8];
        #pragma unroll
        for (int i = 0; i < 8; i++)
            #pragma unroll
            for (int j = 0; j < 8; j++) acc[i][j] = 0.f;

        for (int kk2 = 0; kk2 < 64; kk2 += 32) {
            // stage X tile (128 rows x 32 dk), transposed
            #pragma unroll
            for (int it = 0; it < 4; it++) {
                const int idx = it * 256 + tid;   // 0..1023
                const int row = idx >> 3;
                const int d4  = (idx & 7) * 4;
                const int grow = rowblk * 128 + row;
                const float* src = (grow < 256) ? (qin + grow * D)
                                 : (grow < 320) ? (kin + (grow - 256) * D)
                                                : (vin + (grow - 320) * D);
                const float4 xv = *(const float4*)(src + kbase + kk2 + d4);
                sh.p1.XsT[d4 + 0][row] = xv.x; sh.p1.XsT[d4 + 1][row] = xv.y;
                sh.p1.XsT[d4 + 2][row] = xv.z; sh.p1.XsT[d4 + 3][row] = xv.w;
            }
            // stage both W tiles (2 x 32 dk x 128 cols)
            #pragma unroll
            for (int it = 0; it < 8; it++) {
                const int idx  = it * 256 + tid;  // 0..2047
                const int half = idx >> 10;
                const int rem  = idx & 1023;
                const int dk   = rem >> 5;
                const int c4   = (rem & 31) * 4;
                const float* Wsel = half ? Whi : Wlo;
                *(float4*)&sh.p1.Ws2[half][dk][c4] =
                    *(const float4*)(Wsel + (kbase + kk2 + dk) * D + col0 + c4);
            }
            __syncthreads();
            #pragma unroll
            for (int dk = 0; dk < 32; dk++) {
                const float4 x0 = *(const float4*)&sh.p1.XsT[dk][r0];
                const float4 x1 = *(const float4*)&sh.p1.XsT[dk][r0 + 4];
                const float4 w0 = *(const float4*)&sh.p1.Ws2[hw][dk][c0];
                const float4 w1 = *(const float4*)&sh.p1.Ws2[hw][dk][c0 + 4];
                const float xr[8] = {x0.x, x0.y, x0.z, x0.w, x1.x, x1.y, x1.z, x1.w};
                const float wc[8] = {w0.x, w0.y, w0.z, w0.w, w1.x, w1.y, w1.z, w1.w};
                #pragma unroll
                for (int i = 0; i < 8; i++)
                    #pragma unroll
                    for (int j = 0; j < 8; j++)
                        acc[i][j] = fmaf(xr[i], wc[j], acc[i][j]);
            }
            __syncthreads();
        }
        float* P = ws + OFF_PP + ks * (ROWS * D);
        #pragma unroll
        for (int i = 0; i < 8; i++) {
            float* base = P + (rowblk * 128 + r0 + i) * D + col0 + c0;
            *(float4*)(base)     = make_float4(acc[i][0], acc[i][1], acc[i][2], acc[i][3]);
            *(float4*)(base + 4) = make_float4(acc[i][4], acc[i][5], acc[i][6], acc[i][7]);
        }
    }
    grid_barrier(bar, 0);

    // -----------------------------------------------------------------
    // Phase 2: sum 12 splitK partials + bias -> Pf.  288 jobs.
    // -----------------------------------------------------------------
    for (int j = bid; j < 288; j += NBLK) {
        const int idx = (j * 256 + tid) * 4;      // < 294912
        const float* PP = ws + OFF_PP;
        float4 acc4 = *(const float4*)(PP + idx);
        #pragma unroll
        for (int c = 1; c < SPLITK; c++) {
            const float4 p = *(const float4*)(PP + c * (ROWS * D) + idx);
            acc4.x += p.x; acc4.y += p.y; acc4.z += p.z; acc4.w += p.w;
        }
        const int row = idx / D, col = idx % D;
        const float* bias = (row < 256) ? bq : (row < 320) ? bk : bv;
        const float4 bb = *(const float4*)(bias + col);
        acc4.x += bb.x; acc4.y += bb.y; acc4.z += bb.z; acc4.w += bb.w;
        *(float4*)(ws + OFF_PF + idx) = acc4;
    }
    grid_barrier(bar, 1);

    // -----------------------------------------------------------------
    // Phase 3: A[nh][e][q] = mem_e . Q_q ; B[nh][k][q] = K_k . Q_q.
    // 192 jobs = (64 nh, 3 rowgroups of 128).
    // -----------------------------------------------------------------
    if (bid < 192) {
        const int nh = bid & 63;
        const int rg = bid >> 6;                  // 0..2
        const int n = nh >> 4, h = nh & 15;
        const float* Pf = ws + OFF_PF;
        float* A = ws + OFF_A;
        float* B = ws + OFF_B;

        #pragma unroll
        for (int it = 0; it < 6; it++) {          // stage 128 rows x 48 d, transposed
            const int idx = it * 256 + tid;       // 0..1535
            const int row = idx / 12;
            const int d4  = (idx % 12) * 4;
            const int rr = rg * 128 + row;
            float4 rv = make_float4(0.f, 0.f, 0.f, 0.f);
            if (rr < E)            rv = *(const float4*)(memo + rr * D + h * HD + d4);
            else if (rr < E + KL)  rv = *(const float4*)(Pf + (256 + rr - E) * D + h * HD + d4);
            sh.p3.RsT[d4 + 0][row] = rv.x; sh.p3.RsT[d4 + 1][row] = rv.y;
            sh.p3.RsT[d4 + 2][row] = rv.z; sh.p3.RsT[d4 + 3][row] = rv.w;
        }
        #pragma unroll
        for (int it = 0; it < 3; it++) {          // stage Q slice 64 q x 48 d, transposed
            const int idx = it * 256 + tid;       // 0..767
            const int q  = idx / 12;
            const int d4 = (idx % 12) * 4;
            const float4 qv = *(const float4*)(Pf + (n * QL + q) * D + h * HD + d4);
            sh.p3.QsT[d4 + 0][q] = qv.x; sh.p3.QsT[d4 + 1][q] = qv.y;
            sh.p3.QsT[d4 + 2][q] = qv.z; sh.p3.QsT[d4 + 3][q] = qv.w;
        }
        __syncthreads();

        const int r0 = (tid >> 4) * 8;            // 0..120
        const int q0 = (tid & 15) * 4;            // 0..60
        float acc[8][4];
        #pragma unroll
        for (int i = 0; i < 8; i++)
            #pragma unroll
            for (int j = 0; j < 4; j++) acc[i][j] = 0.f;

        #pragma unroll 4
        for (int d = 0; d < HD; d++) {
            const float4 rf0 = *(const float4*)&sh.p3.RsT[d][r0];
            const float4 rf1 = *(const float4*)&sh.p3.RsT[d][r0 + 4];
            const float4 qf  = *(const float4*)&sh.p3.QsT[d][q0];
            const float rr8[8] = {rf0.x, rf0.y, rf0.z, rf0.w, rf1.x, rf1.y, rf1.z, rf1.w};
            const float qq4[4] = {qf.x, qf.y, qf.z, qf.w};
            #pragma unroll
            for (int i = 0; i < 8; i++)
                #pragma unroll
                for (int j = 0; j < 4; j++)
                    acc[i][j] = fmaf(rr8[i], qq4[j], acc[i][j]);
        }
        #pragma unroll
        for (int i = 0; i < 8; i++) {
            const int rr = rg * 128 + r0 + i;
            const float4 av = make_float4(acc[i][0], acc[i][1], acc[i][2], acc[i][3]);
            if (rr < E)            *(float4*)(A + (nh * E + rr) * QL + q0) = av;
            else if (rr < E + KL)  *(float4*)(B + (nh * KL + (rr - E)) * QL + q0) = av;
        }
    }
    grid_barrier(bar, 2);

    // -----------------------------------------------------------------
    // Phase 4: fused core.  256 jobs = (64 nh, 4 e-chunk groups of 75).
    // wave w owns e-sub-chunk of 19; lane = k; 64 q in registers.
    // -----------------------------------------------------------------
    {
        const int nh = bid & 63;
        const int eg = bid >> 6;                  // 0..3
        const int lane = tid & 63;                // k
        const int w = tid >> 6;                   // 0..3

        const float* Ag = ws + OFF_A + (nh * E + eg * 75) * QL;
        for (int idx = tid; idx < 1200; idx += 256)
            *(float4*)&sh.p4.As[idx * 4] = *(const float4*)(Ag + idx * 4);
        const float* Bg = ws + OFF_B + nh * (KL * QL);
        #pragma unroll
        for (int it = 0; it < 4; it++) {
            const int idx = it * 256 + tid;       // 0..1023
            const int k  = idx >> 4;
            const int q4 = (idx & 15) * 4;
            *(float4*)&sh.p4.Bs[k][q4] = *(const float4*)(Bg + idx * 4);
        }
        __syncthreads();

        float b[64];
        #pragma unroll
        for (int j = 0; j < 16; j++)
            *(float4*)&b[j * 4] = *(const float4*)&sh.p4.Bs[lane][j * 4];

        float s[64];
        #pragma unroll
        for (int j = 0; j < 64; j++) s[j] = 0.f;

        const int eBeg = w * 19;
        const int eEnd = (eBeg + 19 < 75) ? eBeg + 19 : 75;
        for (int e = eBeg; e < eEnd; e++) {
            float m[64];
            #pragma unroll
            for (int j4 = 0; j4 < 16; j4++) {
                const float4 a = *(const float4*)&sh.p4.As[e * 64 + j4 * 4];  // broadcast
                m[j4 * 4 + 0] = fmaxf(a.x + b[j4 * 4 + 0], 0.f);
                m[j4 * 4 + 1] = fmaxf(a.y + b[j4 * 4 + 1], 0.f);
                m[j4 * 4 + 2] = fmaxf(a.z + b[j4 * 4 + 2], 0.f);
                m[j4 * 4 + 3] = fmaxf(a.w + b[j4 * 4 + 3], 0.f);
            }
            float p0 = 0.f, p1 = 0.f, p2 = 0.f, p3 = 0.f;
            #pragma unroll
            for (int j4 = 0; j4 < 16; j4++) {
                p0 += m[j4 * 4 + 0]; p1 += m[j4 * 4 + 1];
                p2 += m[j4 * 4 + 2]; p3 += m[j4 * 4 + 3];
            }
            const float p = (p0 + p1) + (p2 + p3);
            #pragma unroll
            for (int j = 0; j < 64; j++)
                s[j] = fmaf(m[j], p, s[j]);
        }

        float* Sp = ws + OFF_SP + (((eg * 4 + w) * NH + nh) * QL) * KL;
        #pragma unroll
        for (int q = 0; q < 64; q++)
            Sp[q * KL + lane] = s[q];
    }
    grid_barrier(bar, 3);

    // -----------------------------------------------------------------
    // Phase 5: S = sum of 16 partials; out = S @ V.  256 jobs.
    // -----------------------------------------------------------------
    {
        const int nh = bid & 63;
        const int qq = bid >> 6;
        const int n = nh >> 4, h = nh & 15;
        const int q0 = qq * 16;
        const float* Sp = ws + OFF_SP;
        const float* Pf = ws + OFF_PF;

        #pragma unroll
        for (int it = 0; it < 4; it++) {          // sum 16 partials
            const int idx = it * 256 + tid;       // 0..1023
            const int qi = idx >> 6, k = idx & 63;
            float sum = 0.f;
            #pragma unroll
            for (int c = 0; c < NCH; c++)
                sum += Sp[((c * NH + nh) * QL + q0 + qi) * KL + k];
            sh.p5.S_l[qi][k] = sum;
        }
        #pragma unroll
        for (int it = 0; it < 3; it++) {          // stage V slice
            const int idx = it * 256 + tid;       // 0..767
            const int k  = idx / 12;
            const int d4 = (idx % 12) * 4;
            *(float4*)&sh.p5.V_l[k][d4] = *(const float4*)(Pf + (320 + k) * D + h * HD + d4);
        }
        __syncthreads();

        const int qi = tid >> 4;                  // 0..15
        const int dg = tid & 15;                  // 0..15, 12 active
        if (dg < 12) {
            float a0 = 0.f, a1 = 0.f, a2 = 0.f, a3 = 0.f;
            #pragma unroll 8
            for (int k = 0; k < KL; k++) {
                const float sv = sh.p5.S_l[qi][k];
                const float4 vf = *(const float4*)&sh.p5.V_l[k][dg * 4];
                a0 = fmaf(sv, vf.x, a0); a1 = fmaf(sv, vf.y, a1);
                a2 = fmaf(sv, vf.z, a2); a3 = fmaf(sv, vf.w, a3);
            }
            *(float4*)(outp + (n * QL + q0 + qi) * D + h * HD + dg * 4) =
                make_float4(a0, a1, a2, a3);
        }
    }
}

// ---------------------------------------------------------------------------
extern "C" void kernel_launch(void* const* d_in, const int* in_sizes, int n_in,
                              void* d_out, int out_size, void* d_ws, size_t ws_size,
                              hipStream_t stream)
{
    const float* q    = (const float*)d_in[0];
    const float* k    = (const float*)d_in[1];
    const float* v    = (const float*)d_in[2];
    const float* Wq   = (const float*)d_in[3];
    const float* bq   = (const float*)d_in[4];
    const float* Wk   = (const float*)d_in[5];
    const float* bk   = (const float*)d_in[6];
    const float* Wv   = (const float*)d_in[7];
    const float* bv   = (const float*)d_in[8];
    const float* memo = (const float*)d_in[9];
    float* ws   = (float*)d_ws;
    float* outp = (float*)d_out;

    // zero the 4 grid-barrier counters (re-zeroed on every graph replay)
    hipMemsetAsync(ws + OFF_BAR, 0, 4 * sizeof(unsigned), stream);

    hipLaunchKernelGGL(fused_kernel, dim3(NBLK), dim3(256), 0, stream,
                       q, k, v, Wq, Wk, Wv, bq, bk, bv, memo, ws, outp);
}

// Round 3
// 121.830 us; speedup vs baseline: 1.9089x; 1.9089x over previous
//
#include <hip/hip_runtime.h>

// Problem constants
#define H   16
#define E   300
#define D   768
#define HD  48
#define QL  64
#define KL  64
#define NH  64          // n(4) * h(16)
#define ROWS 384        // 256 Q rows + 64 K + 64 V
#define SPLITK 12
#define NCH 4           // e-chunk partial count (one per block; waves reduced in LDS)

// Workspace float offsets
#define OFF_PP 0                              // Ppart[12][384][768]
#define OFF_PF (SPLITK*ROWS*D)                // 3,538,944  Pf[384][768]
#define OFF_A  (OFF_PF + ROWS*D)              // 3,833,856  A[nh][e][q]
#define OFF_B  (OFF_A + NH*E*QL)              // 5,062,656  B[nh][k][q]
#define OFF_SP (OFF_B + NH*KL*QL)             // 5,324,800  Sp[4][nh][q][k]
// end = 6,373,376 floats = 25.5 MB

// ---------------------------------------------------------------------------
// K1: QKV projection.  BM=64, BN=128, BK=32, splitK=12 (K-chunk 64).
// grid (6 rowblk, 6 colblk, 12 ks) = 432 blocks (2/CU -> 8 waves/CU), 256 thr,
// 4x8 microtile.  Each 64-row block maps to exactly one of Q/K/V -> single W.
// ---------------------------------------------------------------------------
__global__ __launch_bounds__(256, 2) void proj_kernel(
    const float* __restrict__ qin, const float* __restrict__ kin, const float* __restrict__ vin,
    const float* __restrict__ Wq, const float* __restrict__ Wk, const float* __restrict__ Wv,
    float* __restrict__ ws)
{
    const int rowblk = blockIdx.x;            // 0..5 (64 rows each)
    const int col0   = blockIdx.y * 128;      // 0..640
    const int ks     = blockIdx.z;            // 0..11
    const int kbase  = ks * 64;

    const float* W = (rowblk < 4) ? Wq : (rowblk == 4) ? Wk : Wv;

    __shared__ float XsT[32][68];             // [dk][row], padded
    __shared__ float Ws[32][128];             // [dk][col]

    const int tid = threadIdx.x;
    const int r0  = (tid >> 4) * 4;           // 0..60
    const int c0  = (tid & 15) * 8;           // 0..120

    float acc[4][8];
    #pragma unroll
    for (int i = 0; i < 4; i++)
        #pragma unroll
        for (int j = 0; j < 8; j++) acc[i][j] = 0.f;

    for (int kk2 = 0; kk2 < 64; kk2 += 32) {
        // stage X tile (64 rows x 32 dk), transposed
        #pragma unroll
        for (int it = 0; it < 2; it++) {
            const int idx = it * 256 + tid;   // 0..511
            const int row = idx >> 3;         // 0..63
            const int d4  = (idx & 7) * 4;    // 0..28
            const int grow = rowblk * 64 + row;
            const float* src = (grow < 256) ? (qin + grow * D)
                             : (grow < 320) ? (kin + (grow - 256) * D)
                                            : (vin + (grow - 320) * D);
            const float4 xv = *(const float4*)(src + kbase + kk2 + d4);
            XsT[d4 + 0][row] = xv.x; XsT[d4 + 1][row] = xv.y;
            XsT[d4 + 2][row] = xv.z; XsT[d4 + 3][row] = xv.w;
        }
        // stage W tile (32 dk x 128 cols)
        #pragma unroll
        for (int it = 0; it < 4; it++) {
            const int idx = it * 256 + tid;   // 0..1023
            const int dk  = idx >> 5;         // 0..31
            const int c4  = (idx & 31) * 4;   // 0..124
            *(float4*)&Ws[dk][c4] =
                *(const float4*)(W + (kbase + kk2 + dk) * D + col0 + c4);
        }
        __syncthreads();
        #pragma unroll
        for (int dk = 0; dk < 32; dk++) {
            const float4 x0 = *(const float4*)&XsT[dk][r0];
            const float4 w0 = *(const float4*)&Ws[dk][c0];
            const float4 w1 = *(const float4*)&Ws[dk][c0 + 4];
            const float xr[4] = {x0.x, x0.y, x0.z, x0.w};
            const float wc[8] = {w0.x, w0.y, w0.z, w0.w, w1.x, w1.y, w1.z, w1.w};
            #pragma unroll
            for (int i = 0; i < 4; i++)
                #pragma unroll
                for (int j = 0; j < 8; j++)
                    acc[i][j] = fmaf(xr[i], wc[j], acc[i][j]);
        }
        __syncthreads();
    }
    float* P = ws + OFF_PP + ks * (ROWS * D);
    #pragma unroll
    for (int i = 0; i < 4; i++) {
        float* base = P + (rowblk * 64 + r0 + i) * D + col0 + c0;
        *(float4*)(base)     = make_float4(acc[i][0], acc[i][1], acc[i][2], acc[i][3]);
        *(float4*)(base + 4) = make_float4(acc[i][4], acc[i][5], acc[i][6], acc[i][7]);
    }
}

// ---------------------------------------------------------------------------
// K2: sum 12 splitK partials + bias -> Pf.  grid 288 x 256, 4 floats/thread.
// ---------------------------------------------------------------------------
__global__ __launch_bounds__(256) void reduce_kernel(
    const float* __restrict__ bq, const float* __restrict__ bk, const float* __restrict__ bv,
    float* __restrict__ ws)
{
    const int idx = (blockIdx.x * 256 + threadIdx.x) * 4;   // < 294912
    const float* PP = ws + OFF_PP;
    float4 v = *(const float4*)(PP + idx);
    #pragma unroll
    for (int c = 1; c < SPLITK; c++) {
        const float4 p = *(const float4*)(PP + c * (ROWS * D) + idx);
        v.x += p.x; v.y += p.y; v.z += p.z; v.w += p.w;
    }
    const int row = idx / D, col = idx % D;
    const float* bias = (row < 256) ? bq : (row < 320) ? bk : bv;
    const float4 b = *(const float4*)(bias + col);
    v.x += b.x; v.y += b.y; v.z += b.z; v.w += b.w;
    *(float4*)(ws + OFF_PF + idx) = v;
}

// ---------------------------------------------------------------------------
// K3: A[nh][e][q] = mem_e . Q_q ; B[nh][k][q] = K_k . Q_q.
// Combined rows: 0..299 memory, 300..363 K.  Block: (nh, rowgroup of 128).
// Transposed LDS tiles, 8x4 microtile, b128 reads.  grid (64, 3) = 192.
// ---------------------------------------------------------------------------
__global__ __launch_bounds__(256) void ab_kernel(
    const float* __restrict__ memo, float* __restrict__ ws)
{
    const int nh = blockIdx.x;
    const int rg = blockIdx.y;                // 0..2
    const int n = nh >> 4, h = nh & 15;
    const float* Pf = ws + OFF_PF;
    float* A = ws + OFF_A;
    float* B = ws + OFF_B;

    __shared__ float RsT[48][132];            // [d][row]
    __shared__ float QsT[48][68];             // [d][q]

    const int tid = threadIdx.x;
    #pragma unroll
    for (int it = 0; it < 6; it++) {          // stage 128 rows x 48 d, transposed
        const int idx = it * 256 + tid;       // 0..1535
        const int row = idx / 12;
        const int d4  = (idx % 12) * 4;
        const int rr = rg * 128 + row;
        float4 rv = make_float4(0.f, 0.f, 0.f, 0.f);
        if (rr < E)            rv = *(const float4*)(memo + rr * D + h * HD + d4);
        else if (rr < E + KL)  rv = *(const float4*)(Pf + (256 + rr - E) * D + h * HD + d4);
        RsT[d4 + 0][row] = rv.x; RsT[d4 + 1][row] = rv.y;
        RsT[d4 + 2][row] = rv.z; RsT[d4 + 3][row] = rv.w;
    }
    #pragma unroll
    for (int it = 0; it < 3; it++) {          // stage Q slice 64 q x 48 d, transposed
        const int idx = it * 256 + tid;       // 0..767
        const int q  = idx / 12;
        const int d4 = (idx % 12) * 4;
        const float4 qv = *(const float4*)(Pf + (n * QL + q) * D + h * HD + d4);
        QsT[d4 + 0][q] = qv.x; QsT[d4 + 1][q] = qv.y;
        QsT[d4 + 2][q] = qv.z; QsT[d4 + 3][q] = qv.w;
    }
    __syncthreads();

    const int r0 = (tid >> 4) * 8;            // 0..120
    const int q0 = (tid & 15) * 4;            // 0..60
    float acc[8][4];
    #pragma unroll
    for (int i = 0; i < 8; i++)
        #pragma unroll
        for (int j = 0; j < 4; j++) acc[i][j] = 0.f;

    #pragma unroll 4
    for (int d = 0; d < HD; d++) {
        const float4 rf0 = *(const float4*)&RsT[d][r0];
        const float4 rf1 = *(const float4*)&RsT[d][r0 + 4];
        const float4 qf  = *(const float4*)&QsT[d][q0];
        const float rr8[8] = {rf0.x, rf0.y, rf0.z, rf0.w, rf1.x, rf1.y, rf1.z, rf1.w};
        const float qq4[4] = {qf.x, qf.y, qf.z, qf.w};
        #pragma unroll
        for (int i = 0; i < 8; i++)
            #pragma unroll
            for (int j = 0; j < 4; j++)
                acc[i][j] = fmaf(rr8[i], qq4[j], acc[i][j]);
    }
    #pragma unroll
    for (int i = 0; i < 8; i++) {
        const int rr = rg * 128 + r0 + i;
        const float4 av = make_float4(acc[i][0], acc[i][1], acc[i][2], acc[i][3]);
        if (rr < E)            *(float4*)(A + (nh * E + rr) * QL + q0) = av;
        else if (rr < E + KL)  *(float4*)(B + (nh * KL + (rr - E)) * QL + q0) = av;
    }
}

// ---------------------------------------------------------------------------
// K4: fused core.  Block = (nh, eg of 75 e); wave w owns e-chunk of 19.
// lane = k; all 64 q in registers.  After the e-loop the 4 wave-partials are
// reduced IN-BLOCK through LDS (reusing the As/Bs space - Bs is consumed into
// registers before the e-loop), so each block writes ONE partial:
// Sp[eg][nh][q][k].  grid (64,4).
// ---------------------------------------------------------------------------
__global__ __launch_bounds__(256, 1) void main_kernel(float* __restrict__ ws)
{
    const int nh = blockIdx.x;
    const int eg = blockIdx.y;                // 0..3
    const int tid = threadIdx.x;
    const int lane = tid & 63;                // k
    const int w = tid >> 6;                   // 0..3

    __shared__ union {
        struct { float As[75 * 64]; float Bs[64][68]; } a;   // 36.6 KB
        struct { float r0[64 * 64]; float r1[64 * 64]; } r;  // 32 KB overlay
    } sh;

    const float* Ag = ws + OFF_A + (nh * E + eg * 75) * QL;
    for (int idx = tid; idx < 1200; idx += 256)
        *(float4*)&sh.a.As[idx * 4] = *(const float4*)(Ag + idx * 4);
    const float* Bg = ws + OFF_B + nh * (KL * QL);
    #pragma unroll
    for (int it = 0; it < 4; it++) {
        const int idx = it * 256 + tid;       // 0..1023
        const int k  = idx >> 4;
        const int q4 = (idx & 15) * 4;
        *(float4*)&sh.a.Bs[k][q4] = *(const float4*)(Bg + idx * 4);
    }
    __syncthreads();

    float b[64];
    #pragma unroll
    for (int j = 0; j < 16; j++)
        *(float4*)&b[j * 4] = *(const float4*)&sh.a.Bs[lane][j * 4];

    float s[64];
    #pragma unroll
    for (int j = 0; j < 64; j++) s[j] = 0.f;

    const int eBeg = w * 19;
    const int eEnd = (eBeg + 19 < 75) ? eBeg + 19 : 75;
    for (int e = eBeg; e < eEnd; e++) {
        float m[64];
        #pragma unroll
        for (int j4 = 0; j4 < 16; j4++) {
            const float4 a = *(const float4*)&sh.a.As[e * 64 + j4 * 4];  // broadcast
            m[j4 * 4 + 0] = fmaxf(a.x + b[j4 * 4 + 0], 0.f);
            m[j4 * 4 + 1] = fmaxf(a.y + b[j4 * 4 + 1], 0.f);
            m[j4 * 4 + 2] = fmaxf(a.z + b[j4 * 4 + 2], 0.f);
            m[j4 * 4 + 3] = fmaxf(a.w + b[j4 * 4 + 3], 0.f);
        }
        float p0 = 0.f, p1 = 0.f, p2 = 0.f, p3 = 0.f;
        #pragma unroll
        for (int j4 = 0; j4 < 16; j4++) {
            p0 += m[j4 * 4 + 0]; p1 += m[j4 * 4 + 1];
            p2 += m[j4 * 4 + 2]; p3 += m[j4 * 4 + 3];
        }
        const float p = (p0 + p1) + (p2 + p3);
        #pragma unroll
        for (int j = 0; j < 64; j++)
            s[j] = fmaf(m[j], p, s[j]);
    }

    // In-block reduction of the 4 wave partials (tree through LDS).
    // All waves are done reading As/Bs here; the r-overlay may clobber them.
    __syncthreads();
    if (w >= 2) {
        float* red = (w == 2) ? sh.r.r0 : sh.r.r1;
        #pragma unroll
        for (int q = 0; q < 64; q++) red[q * 64 + lane] = s[q];
    }
    __syncthreads();
    if (w == 0) {
        #pragma unroll
        for (int q = 0; q < 64; q++) s[q] += sh.r.r0[q * 64 + lane];
    } else if (w == 1) {
        #pragma unroll
        for (int q = 0; q < 64; q++) s[q] += sh.r.r1[q * 64 + lane];
    }
    __syncthreads();
    if (w == 1) {
        #pragma unroll
        for (int q = 0; q < 64; q++) sh.r.r0[q * 64 + lane] = s[q];
    }
    __syncthreads();
    if (w == 0) {
        float* Sp = ws + OFF_SP + ((eg * NH + nh) * QL) * KL;
        #pragma unroll
        for (int q = 0; q < 64; q++)
            Sp[q * KL + lane] = s[q] + sh.r.r0[q * 64 + lane];
    }
}

// ---------------------------------------------------------------------------
// K5: S = sum of 4 partials;  out[n,q,h,d] = sum_k S[q,k] * V[k,h,d]
// grid (64 nh, 4 q-quarters), 256 thr; thread = (qi, d-group of 4), b128 V.
// ---------------------------------------------------------------------------
__global__ __launch_bounds__(256) void out_kernel(
    const float* __restrict__ ws_c, float* __restrict__ outp)
{
    const int nh = blockIdx.x;
    const int qq = blockIdx.y;
    const int n = nh >> 4, h = nh & 15;
    const int q0 = qq * 16;
    const float* Sp = ws_c + OFF_SP;
    const float* Pf = ws_c + OFF_PF;

    __shared__ float S_l[16][64];
    __shared__ float V_l[64][52];             // 52: b128-aligned rows

    const int tid = threadIdx.x;
    #pragma unroll
    for (int it = 0; it < 4; it++) {          // sum 4 partials
        const int idx = it * 256 + tid;       // 0..1023
        const int qi = idx >> 6, k = idx & 63;
        float sum = 0.f;
        #pragma unroll
        for (int c = 0; c < NCH; c++)
            sum += Sp[((c * NH + nh) * QL + q0 + qi) * KL + k];
        S_l[qi][k] = sum;
    }
    #pragma unroll
    for (int it = 0; it < 3; it++) {          // stage V slice
        const int idx = it * 256 + tid;       // 0..767
        const int k  = idx / 12;
        const int d4 = (idx % 12) * 4;
        *(float4*)&V_l[k][d4] = *(const float4*)(Pf + (320 + k) * D + h * HD + d4);
    }
    __syncthreads();

    const int qi = tid >> 4;                  // 0..15
    const int dg = tid & 15;                  // 0..15, 12 active
    if (dg < 12) {
        float a0 = 0.f, a1 = 0.f, a2 = 0.f, a3 = 0.f;
        #pragma unroll 8
        for (int k = 0; k < KL; k++) {
            const float sv = S_l[qi][k];
            const float4 vf = *(const float4*)&V_l[k][dg * 4];
            a0 = fmaf(sv, vf.x, a0); a1 = fmaf(sv, vf.y, a1);
            a2 = fmaf(sv, vf.z, a2); a3 = fmaf(sv, vf.w, a3);
        }
        *(float4*)(outp + (n * QL + q0 + qi) * D + h * HD + dg * 4) =
            make_float4(a0, a1, a2, a3);
    }
}

// ---------------------------------------------------------------------------
extern "C" void kernel_launch(void* const* d_in, const int* in_sizes, int n_in,
                              void* d_out, int out_size, void* d_ws, size_t ws_size,
                              hipStream_t stream)
{
    const float* q    = (const float*)d_in[0];
    const float* k    = (const float*)d_in[1];
    const float* v    = (const float*)d_in[2];
    const float* Wq   = (const float*)d_in[3];
    const float* bq   = (const float*)d_in[4];
    const float* Wk   = (const float*)d_in[5];
    const float* bk   = (const float*)d_in[6];
    const float* Wv   = (const float*)d_in[7];
    const float* bv   = (const float*)d_in[8];
    const float* memo = (const float*)d_in[9];
    float* ws   = (float*)d_ws;
    float* outp = (float*)d_out;

    hipLaunchKernelGGL(proj_kernel, dim3(6, 6, 12), dim3(256), 0, stream,
                       q, k, v, Wq, Wk, Wv, ws);
    hipLaunchKernelGGL(reduce_kernel, dim3(288), dim3(256), 0, stream, bq, bk, bv, ws);
    hipLaunchKernelGGL(ab_kernel, dim3(64, 3), dim3(256), 0, stream, memo, ws);
    hipLaunchKernelGGL(main_kernel, dim3(64, 4), dim3(256), 0, stream, ws);
    hipLaunchKernelGGL(out_kernel, dim3(64, 4), dim3(256), 0, stream, ws, outp);
}